// Round 11
// baseline (87.508 us; speedup 1.0000x reference)
//
#include <hip/hip_runtime.h>
#include <math.h>

#define NB 1024   // batch
#define NC 64     // input dim
#define NH 128    // hidden dim
#define MAX_IT 500
#define TOLF 1e-3f

typedef _Float16 f16x8 __attribute__((ext_vector_type(8)));
typedef float    f32x4 __attribute__((ext_vector_type(4)));
typedef _Float16 h2    __attribute__((ext_vector_type(2)));

#define MFMA(a, b, c) __builtin_amdgcn_mfma_f32_16x16x32_f16((a), (b), (c), 0, 0, 0)

__device__ __forceinline__ unsigned pack_h2(float a, float b) {
    union { h2 h; unsigned u; } cv;
    cv.h.x = (_Float16)a; cv.h.y = (_Float16)b; return cv.u;
}
__device__ __forceinline__ float rcp_fast(float x) {
#if __has_builtin(__builtin_amdgcn_rcpf)
    return __builtin_amdgcn_rcpf(x);
#else
    return 1.0f / x;
#endif
}
// sigmoid + softplus sharing one exp
__device__ __forceinline__ void sigsp(float a, float& sig, float& sp) {
    const float e = __expf(-fabsf(a));
    const float r = rcp_fast(1.0f + e);
    sig = (a >= 0.0f) ? r : e * r;
    sp  = fmaxf(a, 0.0f) + __logf(1.0f + e);
}
__device__ __forceinline__ float clp(float x) { return fmaxf(x, 0.0f); }

// R11: R10's register hoist was silently rematerialized (dur flat; 190
// ds_read_b128/CU/iter ~ 2280 cyc matches measured 2400). Fix mechanism:
// pin every A-frag with asm "+a" -> value is OPAQUE (no remat possible) and
// lives in AGPRs. MFMA reads A-operands from AGPRs natively on gfx950
// (unified file), so the builtin consumes them in place — no copy-back
// failure mode (R7's VALU consumers couldn't do this). Loop LDS becomes
// activations only (~62 inst/CU/iter).
__launch_bounds__(256, 1)
__global__ void blnn_kernel(const float* __restrict__ xin,
                            const float* __restrict__ Wy0,
                            const float* __restrict__ by0,
                            const float* __restrict__ Wy1,
                            const float* __restrict__ by1,
                            const float* __restrict__ Wz1,
                            const float* __restrict__ Wy2,
                            const float* __restrict__ by2,
                            const float* __restrict__ Wz2,
                            float* __restrict__ out)
{
    // A-frag weight tiles: [tile][lane] uint4 (8 fp16). tile = mt*KS + ks.
    __shared__ uint4 WA0q[16 * 64];   // Wy0   (M=128,K=64):  mt8 x ks2
    __shared__ uint4 WA1q[16 * 64];   // Wy1
    __shared__ uint4 WAZq[32 * 64];   // Wz1+  (M=128,K=128): mt8 x ks4
    __shared__ uint4 WZTq[32 * 64];   // Wz1+^T
    __shared__ uint4 W1Tq[16 * 64];   // Wy1^T (M=64,K=128):  mt4 x ks4
    __shared__ uint4 W0Tq[16 * 64];   // Wy0^T
    __shared__ __align__(16) _Float16 xact [4 * 72];   // x  per sample
    __shared__ __align__(16) _Float16 h0act[4 * 136];  // h0 per sample
    __shared__ __align__(16) _Float16 v1act[4 * 136];
    __shared__ __align__(16) _Float16 v0act[4 * 136];
    __shared__ __align__(16) float by0f[128], by1f[128], wz2f[128];
    __shared__ __align__(16) float hp[16], pxp[16], npar[16];   // [n][w]

    const int tid  = threadIdx.x;
    const int w    = tid >> 6;
    const int l    = tid & 63;
    const int n    = l & 15;          // MFMA col
    const int n4   = n & 3;           // real sample
    const int quad = l >> 4;
    const int blk4 = blockIdx.x * 4;

    // ---- stage weights into A-frag order ----
    for (int f = tid; f < 16 * 64; f += 256) {        // WA0 / WA1
        const int tile = f >> 6, q = f & 63;
        const int mt = tile >> 1, ks = tile & 1;
        const int row = mt * 16 + (q & 15);
        const int k0  = ks * 32 + ((q >> 4) << 3);
        const float* p0 = Wy0 + row * 64 + k0;
        WA0q[f] = make_uint4(pack_h2(p0[0], p0[1]), pack_h2(p0[2], p0[3]),
                             pack_h2(p0[4], p0[5]), pack_h2(p0[6], p0[7]));
        const float* p1 = Wy1 + row * 64 + k0;
        WA1q[f] = make_uint4(pack_h2(p1[0], p1[1]), pack_h2(p1[2], p1[3]),
                             pack_h2(p1[4], p1[5]), pack_h2(p1[6], p1[7]));
    }
    for (int f = tid; f < 32 * 64; f += 256) {        // WAZ / WZT (clip >= 0)
        const int tile = f >> 6, q = f & 63;
        const int mt = tile >> 2, ks = tile & 3;
        const int row = mt * 16 + (q & 15);
        const int k0  = ks * 32 + ((q >> 4) << 3);
        const float* p = Wz1 + row * 128 + k0;
        WAZq[f] = make_uint4(pack_h2(clp(p[0]), clp(p[1])), pack_h2(clp(p[2]), clp(p[3])),
                             pack_h2(clp(p[4]), clp(p[5])), pack_h2(clp(p[6]), clp(p[7])));
        const float* pt = Wz1 + k0 * 128 + row;       // (Wz1^T)[row][k0+j]
        WZTq[f] = make_uint4(pack_h2(clp(pt[0]),   clp(pt[128])),
                             pack_h2(clp(pt[256]), clp(pt[384])),
                             pack_h2(clp(pt[512]), clp(pt[640])),
                             pack_h2(clp(pt[768]), clp(pt[896])));
    }
    for (int f = tid; f < 16 * 64; f += 256) {        // W1T / W0T
        const int tile = f >> 6, q = f & 63;
        const int mt = tile >> 2, ks = tile & 3;
        const int rowT = mt * 16 + (q & 15);          // c in 0..63
        const int k0   = ks * 32 + ((q >> 4) << 3);   // original row
        const float* p1 = Wy1 + k0 * 64 + rowT;
        W1Tq[f] = make_uint4(pack_h2(p1[0],   p1[64]),  pack_h2(p1[128], p1[192]),
                             pack_h2(p1[256], p1[320]), pack_h2(p1[384], p1[448]));
        const float* p0 = Wy0 + k0 * 64 + rowT;
        W0Tq[f] = make_uint4(pack_h2(p0[0],   p0[64]),  pack_h2(p0[128], p0[192]),
                             pack_h2(p0[256], p0[320]), pack_h2(p0[384], p0[448]));
    }
    if (tid < 128) {
        by0f[tid] = by0[tid];
        by1f[tid] = by1[tid];
        wz2f[tid] = fmaxf(Wz2[tid], 0.0f);
    }
    {   // x0 = z into act layout
        const int nn = tid >> 6, cc = tid & 63;
        xact[nn * 72 + cc] = (_Float16)xin[(blk4 + nn) * 64 + cc];
    }

    // ---- per-lane col-role state: rows c = 16w + quad*4 + r, sample n4 ----
    const float4 z4  = ((const float4*)xin)[(blk4 + n4) * 16 + w * 4 + quad];
    const float4 wy4 = ((const float4*)Wy2)[w * 4 + quad];
    float zr[4]   = {z4.x, z4.y, z4.z, z4.w};
    float wy2r[4] = {wy4.x, wy4.y, wy4.z, wy4.w};
    float xcur[4] = {zr[0], zr[1], zr[2], zr[3]};
    float lamE = 1.0f, prevE = 3.4e38f;
    const float b2 = by2[0];

    {   // px = sum_c wy2[c]*x[c] for first iteration
        float pxs = wy2r[0]*xcur[0] + wy2r[1]*xcur[1] + wy2r[2]*xcur[2] + wy2r[3]*xcur[3];
        pxs += __shfl_xor(pxs, 16, 64);
        pxs += __shfl_xor(pxs, 32, 64);
        if (l < 4) pxp[l * 4 + w] = pxs;
    }
    __syncthreads();

    const f16x8* WA0v = (const f16x8*)WA0q;
    const f16x8* WA1v = (const f16x8*)WA1q;
    const f16x8* WAZv = (const f16x8*)WAZq;
    const f16x8* WZTv = (const f16x8*)WZTq;
    const f16x8* W1Tv = (const f16x8*)W1Tq;
    const f16x8* W0Tv = (const f16x8*)W0Tq;
    const float4* by0v = (const float4*)by0f;
    const float4* by1v = (const float4*)by1f;
    const float4* wz2v = (const float4*)wz2f;
    const _Float16* xrow  = xact  + n4 * 72;
    const _Float16* h0row = h0act + n4 * 136;
    const _Float16* v1row = v1act + n4 * 136;
    const _Float16* v0row = v0act + n4 * 136;

    // ---- hoist ALL per-wave A-frag tiles into AGPRs (iteration-invariant).
    // asm "+a": opaque origin (remat illegal) + AGPR class (MFMA reads A
    // from AGPR natively on gfx950 — zero per-use copies).
    f16x8 fa0_00 = WA0v[((w    ) * 2 + 0) * 64 + l];
    f16x8 fa0_01 = WA0v[((w    ) * 2 + 1) * 64 + l];
    f16x8 fa0_10 = WA0v[((w + 4) * 2 + 0) * 64 + l];
    f16x8 fa0_11 = WA0v[((w + 4) * 2 + 1) * 64 + l];
    f16x8 fa1_00 = WA1v[((w    ) * 2 + 0) * 64 + l];
    f16x8 fa1_01 = WA1v[((w    ) * 2 + 1) * 64 + l];
    f16x8 fa1_10 = WA1v[((w + 4) * 2 + 0) * 64 + l];
    f16x8 fa1_11 = WA1v[((w + 4) * 2 + 1) * 64 + l];
    f16x8 faz_00 = WAZv[((w    ) * 4 + 0) * 64 + l];
    f16x8 faz_01 = WAZv[((w    ) * 4 + 1) * 64 + l];
    f16x8 faz_02 = WAZv[((w    ) * 4 + 2) * 64 + l];
    f16x8 faz_03 = WAZv[((w    ) * 4 + 3) * 64 + l];
    f16x8 faz_10 = WAZv[((w + 4) * 4 + 0) * 64 + l];
    f16x8 faz_11 = WAZv[((w + 4) * 4 + 1) * 64 + l];
    f16x8 faz_12 = WAZv[((w + 4) * 4 + 2) * 64 + l];
    f16x8 faz_13 = WAZv[((w + 4) * 4 + 3) * 64 + l];
    f16x8 fzt_00 = WZTv[((w    ) * 4 + 0) * 64 + l];
    f16x8 fzt_01 = WZTv[((w    ) * 4 + 1) * 64 + l];
    f16x8 fzt_02 = WZTv[((w    ) * 4 + 2) * 64 + l];
    f16x8 fzt_03 = WZTv[((w    ) * 4 + 3) * 64 + l];
    f16x8 fzt_10 = WZTv[((w + 4) * 4 + 0) * 64 + l];
    f16x8 fzt_11 = WZTv[((w + 4) * 4 + 1) * 64 + l];
    f16x8 fzt_12 = WZTv[((w + 4) * 4 + 2) * 64 + l];
    f16x8 fzt_13 = WZTv[((w + 4) * 4 + 3) * 64 + l];
    f16x8 ft1_0  = W1Tv[(w * 4 + 0) * 64 + l];
    f16x8 ft1_1  = W1Tv[(w * 4 + 1) * 64 + l];
    f16x8 ft1_2  = W1Tv[(w * 4 + 2) * 64 + l];
    f16x8 ft1_3  = W1Tv[(w * 4 + 3) * 64 + l];
    f16x8 ft0_0  = W0Tv[(w * 4 + 0) * 64 + l];
    f16x8 ft0_1  = W0Tv[(w * 4 + 1) * 64 + l];
    f16x8 ft0_2  = W0Tv[(w * 4 + 2) * 64 + l];
    f16x8 ft0_3  = W0Tv[(w * 4 + 3) * 64 + l];

    asm volatile("" : "+a"(fa0_00), "+a"(fa0_01), "+a"(fa0_10), "+a"(fa0_11),
                      "+a"(fa1_00), "+a"(fa1_01), "+a"(fa1_10), "+a"(fa1_11));
    asm volatile("" : "+a"(faz_00), "+a"(faz_01), "+a"(faz_02), "+a"(faz_03),
                      "+a"(faz_10), "+a"(faz_11), "+a"(faz_12), "+a"(faz_13));
    asm volatile("" : "+a"(fzt_00), "+a"(fzt_01), "+a"(fzt_02), "+a"(fzt_03),
                      "+a"(fzt_10), "+a"(fzt_11), "+a"(fzt_12), "+a"(fzt_13));
    asm volatile("" : "+a"(ft1_0), "+a"(ft1_1), "+a"(ft1_2), "+a"(ft1_3),
                      "+a"(ft0_0), "+a"(ft0_1), "+a"(ft0_2), "+a"(ft0_3));

    float sig0[2][4], sig1[2][4], wzr[2][4];
    float sg2 = 0.0f;

    for (int it = 0; it < MAX_IT; ++it) {
        // ---- P1: preact0 = Wy0 x + by0 -> h0, sig0 ----
        f16x8 bx0 = *(const f16x8*)(xrow + quad * 8);
        f16x8 bx1 = *(const f16x8*)(xrow + 32 + quad * 8);
#define P1_BODY(MI, TA, TB) { \
        const int mt = w + 4 * MI; \
        f32x4 acc = {0.f, 0.f, 0.f, 0.f}; \
        acc = MFMA(TA, bx0, acc); \
        acc = MFMA(TB, bx1, acc); \
        const float4 bb = by0v[mt * 4 + quad]; \
        float sp0, sp1, sp2, sp3; \
        sigsp(acc[0] + bb.x, sig0[MI][0], sp0); \
        sigsp(acc[1] + bb.y, sig0[MI][1], sp1); \
        sigsp(acc[2] + bb.z, sig0[MI][2], sp2); \
        sigsp(acc[3] + bb.w, sig0[MI][3], sp3); \
        if (n < 4) \
            *(uint2*)&h0act[n4 * 136 + mt * 16 + quad * 4] = \
                make_uint2(pack_h2(sp0, sp1), pack_h2(sp2, sp3)); }
        P1_BODY(0, fa0_00, fa0_01)
        P1_BODY(1, fa0_10, fa0_11)
#undef P1_BODY
        __syncthreads();   // (1) h0 ready

        // ---- P2: preact1 = Wz1+ h0 + Wy1 x + by1 -> sig1, h1, head ----
        f16x8 bh0 = *(const f16x8*)(h0row + quad * 8);
        f16x8 bh1 = *(const f16x8*)(h0row + 32 + quad * 8);
        f16x8 bh2 = *(const f16x8*)(h0row + 64 + quad * 8);
        f16x8 bh3 = *(const f16x8*)(h0row + 96 + quad * 8);
        float hsum = 0.0f;
#define P2_BODY(MI, Z0, Z1, Z2, Z3, A0, A1) { \
        const int mt = w + 4 * MI; \
        f32x4 acc = {0.f, 0.f, 0.f, 0.f}; \
        acc = MFMA(Z0, bh0, acc); \
        acc = MFMA(Z1, bh1, acc); \
        acc = MFMA(Z2, bh2, acc); \
        acc = MFMA(Z3, bh3, acc); \
        acc = MFMA(A0, bx0, acc); \
        acc = MFMA(A1, bx1, acc); \
        const float4 bb  = by1v[mt * 4 + quad]; \
        const float4 wzq = wz2v[mt * 4 + quad]; \
        float h1v; \
        sigsp(acc[0] + bb.x, sig1[MI][0], h1v); hsum = fmaf(wzq.x, h1v, hsum); \
        sigsp(acc[1] + bb.y, sig1[MI][1], h1v); hsum = fmaf(wzq.y, h1v, hsum); \
        sigsp(acc[2] + bb.z, sig1[MI][2], h1v); hsum = fmaf(wzq.z, h1v, hsum); \
        sigsp(acc[3] + bb.w, sig1[MI][3], h1v); hsum = fmaf(wzq.w, h1v, hsum); \
        wzr[MI][0] = wzq.x; wzr[MI][1] = wzq.y; wzr[MI][2] = wzq.z; wzr[MI][3] = wzq.w; }
        P2_BODY(0, faz_00, faz_01, faz_02, faz_03, fa1_00, fa1_01)
        P2_BODY(1, faz_10, faz_11, faz_12, faz_13, fa1_10, fa1_11)
#undef P2_BODY
        hsum += __shfl_xor(hsum, 16, 64);
        hsum += __shfl_xor(hsum, 32, 64);
        if (l < 4) hp[l * 4 + w] = hsum;
        __syncthreads();   // (2) head partials ready

        {
            const float4 hv = ((const float4*)hp)[n4];
            const float4 pv = ((const float4*)pxp)[n4];
            const float P = hv.x + hv.y + hv.z + hv.w + pv.x + pv.y + pv.z + pv.w + b2;
            const float e = __expf(-fabsf(P));
            const float r = rcp_fast(1.0f + e);
            sg2 = (P >= 0.0f) ? r : e * r;
        }
        #pragma unroll
        for (int mi = 0; mi < 2; ++mi) {
            const int mt = w + 4 * mi;
            const float a0 = sg2 * sig1[mi][0] * wzr[mi][0];
            const float a1 = sg2 * sig1[mi][1] * wzr[mi][1];
            const float a2 = sg2 * sig1[mi][2] * wzr[mi][2];
            const float a3 = sg2 * sig1[mi][3] * wzr[mi][3];
            if (n < 4)
                *(uint2*)&v1act[n4 * 136 + mt * 16 + quad * 4] =
                    make_uint2(pack_h2(a0, a1), pack_h2(a2, a3));
        }
        __syncthreads();   // (3) v1 ready

        // ---- P4: v0 = sig0 .* (Wz1+^T v1)   +   P6a: Wy1^T v1 ----
        f16x8 bv10 = *(const f16x8*)(v1row + quad * 8);
        f16x8 bv11 = *(const f16x8*)(v1row + 32 + quad * 8);
        f16x8 bv12 = *(const f16x8*)(v1row + 64 + quad * 8);
        f16x8 bv13 = *(const f16x8*)(v1row + 96 + quad * 8);
#define P4_BODY(MI, Z0, Z1, Z2, Z3) { \
        const int mt = w + 4 * MI; \
        f32x4 acc = {0.f, 0.f, 0.f, 0.f}; \
        acc = MFMA(Z0, bv10, acc); \
        acc = MFMA(Z1, bv11, acc); \
        acc = MFMA(Z2, bv12, acc); \
        acc = MFMA(Z3, bv13, acc); \
        const float a0 = sig0[MI][0] * acc[0]; \
        const float a1 = sig0[MI][1] * acc[1]; \
        const float a2 = sig0[MI][2] * acc[2]; \
        const float a3 = sig0[MI][3] * acc[3]; \
        if (n < 4) \
            *(uint2*)&v0act[n4 * 136 + mt * 16 + quad * 4] = \
                make_uint2(pack_h2(a0, a1), pack_h2(a2, a3)); }
        P4_BODY(0, fzt_00, fzt_01, fzt_02, fzt_03)
        P4_BODY(1, fzt_10, fzt_11, fzt_12, fzt_13)
#undef P4_BODY
        f32x4 accg = {0.f, 0.f, 0.f, 0.f};
        accg = MFMA(ft1_0, bv10, accg);
        accg = MFMA(ft1_1, bv11, accg);
        accg = MFMA(ft1_2, bv12, accg);
        accg = MFMA(ft1_3, bv13, accg);
        __syncthreads();   // (4) v0 ready

        // ---- P6b: g = x + sig2*wy2 + Wy1^T v1 + Wy0^T v0 ; residual ----
        f16x8 bv00 = *(const f16x8*)(v0row + quad * 8);
        f16x8 bv01 = *(const f16x8*)(v0row + 32 + quad * 8);
        f16x8 bv02 = *(const f16x8*)(v0row + 64 + quad * 8);
        f16x8 bv03 = *(const f16x8*)(v0row + 96 + quad * 8);
        accg = MFMA(ft0_0, bv00, accg);
        accg = MFMA(ft0_1, bv01, accg);
        accg = MFMA(ft0_2, bv02, accg);
        accg = MFMA(ft0_3, bv03, accg);
        float resid[4];
        float r2 = 0.0f;
        #pragma unroll
        for (int r = 0; r < 4; ++r) {
            const float g = xcur[r] + sg2 * wy2r[r] + accg[r];
            resid[r] = zr[r] - g;
            r2 = fmaf(resid[r], resid[r], r2);
        }
        r2 += __shfl_xor(r2, 16, 64);
        r2 += __shfl_xor(r2, 32, 64);
        if (l < 4) npar[l * 4 + w] = r2;
        __syncthreads();   // (5) norm partials ready

        const float4 q0 = ((const float4*)npar)[0];
        const float4 q1 = ((const float4*)npar)[1];
        const float4 q2 = ((const float4*)npar)[2];
        const float4 q3 = ((const float4*)npar)[3];
        const float s0 = q0.x + q0.y + q0.z + q0.w;
        const float s1 = q1.x + q1.y + q1.z + q1.w;
        const float s2 = q2.x + q2.y + q2.z + q2.w;
        const float s3 = q3.x + q3.y + q3.z + q3.w;
        const float T2 = TOLF * TOLF;
        if (s0 < T2 && s1 < T2 && s2 < T2 && s3 < T2) break;   // uniform

        const float myn2 = (n4 == 0) ? s0 : (n4 == 1) ? s1 : (n4 == 2) ? s2 : s3;
        const float ne = sqrtf(myn2);
        if (ne >= TOLF) {                    // adaptive Richardson (R3 solver)
            if (ne > prevE * 0.999f) lamE *= 0.5f;
            const float step = fmaxf(lamE, 1.0f / (float)(it + 2));
            #pragma unroll
            for (int r = 0; r < 4; ++r) xcur[r] = fmaf(step, resid[r], xcur[r]);
            prevE = ne;
        }
        {   // px partial for next iter + x writeback
            float pxs = wy2r[0]*xcur[0] + wy2r[1]*xcur[1] + wy2r[2]*xcur[2] + wy2r[3]*xcur[3];
            pxs += __shfl_xor(pxs, 16, 64);
            pxs += __shfl_xor(pxs, 32, 64);
            if (l < 4) pxp[l * 4 + w] = pxs;
        }
        if (n < 4)
            *(uint2*)&xact[n4 * 72 + w * 16 + quad * 4] =
                make_uint2(pack_h2(xcur[0], xcur[1]), pack_h2(xcur[2], xcur[3]));
        __syncthreads();   // (6) x ready
    }

    if (n < 4) {
        float4 o;
        o.x = xcur[0] + zr[0]; o.y = xcur[1] + zr[1];
        o.z = xcur[2] + zr[2]; o.w = xcur[3] + zr[3];
        ((float4*)out)[(blk4 + n4) * 16 + w * 4 + quad] = o;   // + CONVEX*z
    }
}

extern "C" void kernel_launch(void* const* d_in, const int* in_sizes, int n_in,
                              void* d_out, int out_size, void* d_ws, size_t ws_size,
                              hipStream_t stream) {
    const float* xin = (const float*)d_in[0];
    const float* Wy0 = (const float*)d_in[1];
    const float* by0 = (const float*)d_in[2];
    const float* Wy1 = (const float*)d_in[3];
    const float* by1 = (const float*)d_in[4];
    const float* Wz1 = (const float*)d_in[5];
    const float* Wy2 = (const float*)d_in[6];
    const float* by2 = (const float*)d_in[7];
    const float* Wz2 = (const float*)d_in[8];
    float* out = (float*)d_out;

    blnn_kernel<<<dim3(NB / 4), dim3(256), 0, stream>>>(
        xin, Wy0, by0, Wy1, by1, Wz1, Wy2, by2, Wz2, out);
}